// Round 1
// baseline (253.841 us; speedup 1.0000x reference)
//
#include <hip/hip_runtime.h>
#include <hip/hip_bf16.h>
#include <stdint.h>

#define ALPHA_LO 0.8187307530779818f
#define ALPHA_HI 0.9607894391523232f

// problem dims
#define BATCH 64
#define TT    2000
#define II    512
#define HH    512
#define MM    (BATCH*TT)   // 128000 rows
#define LCH   50           // chunk length
#define CCH   (TT/LCH)     // 40 chunks

typedef __bf16 bf16;
typedef bf16  bf16x8 __attribute__((ext_vector_type(8)));
typedef bf16  bf16x4 __attribute__((ext_vector_type(4)));
typedef float f32x4  __attribute__((ext_vector_type(4)));

// ---------------- K0: convert W f32 -> bf16 ----------------
__global__ void k_convW(const float* __restrict__ W, bf16* __restrict__ Wb) {
    int i = (blockIdx.x * 256 + threadIdx.x) * 4;
    float4 v = *(const float4*)(W + i);
    bf16x4 o;
    o[0] = (bf16)v.x; o[1] = (bf16)v.y; o[2] = (bf16)v.z; o[3] = (bf16)v.w;
    *(bf16x4*)(Wb + i) = o;
}

// ---------------- K1: GEMM  Y[M,H] = X[M,I] * Wb[H,I]^T  (bf16 MFMA) -------
// 128x128 tile, BK=32, 4 waves (2x2), each wave 64x64 = 4x4 frags of 16x16x32.
__global__ __launch_bounds__(256) void k_gemm(const float* __restrict__ X,
                                              const bf16* __restrict__ Wb,
                                              bf16* __restrict__ Y) {
    __shared__ bf16 Al[128 * 32];
    __shared__ bf16 Bl[128 * 32];
    const int tid = threadIdx.x;
    const int bx  = blockIdx.x;
    const int m0  = (bx >> 2) * 128;   // N-fastest so same-M tiles run adjacently
    const int n0  = (bx & 3) * 128;
    const int lane = tid & 63;
    const int wv   = tid >> 6;
    const int wr   = (wv >> 1) * 64;
    const int wc   = (wv & 1) * 64;
    const int fr   = lane & 15;        // frag row/col
    const int kq   = lane >> 4;        // k-quarter (0..3)

    f32x4 acc[4][4] = {};

    // staging maps
    const int arow = tid >> 3;            // 0..31  (A: 4 rounds of 32 rows)
    const int akk  = (tid & 7) * 4;       // f32 col within BK
    const int brow = tid >> 2;            // 0..63  (B: 2 rounds of 64 rows)
    const int bkk  = (tid & 3) * 8;       // bf16 col within BK

    const float* xa = X  + (size_t)(m0 + arow) * II + akk;
    const bf16*  wb = Wb + (size_t)(n0 + brow) * II + bkk;

    for (int k0 = 0; k0 < II; k0 += 32) {
        __syncthreads();
        float4 av[4];
        #pragma unroll
        for (int r = 0; r < 4; ++r)
            av[r] = *(const float4*)(xa + (size_t)(r * 32) * II + k0);
        bf16x8 bv[2];
        #pragma unroll
        for (int r = 0; r < 2; ++r)
            bv[r] = *(const bf16x8*)(wb + (size_t)(r * 64) * II + k0);
        #pragma unroll
        for (int r = 0; r < 4; ++r) {
            bf16x4 cv;
            cv[0] = (bf16)av[r].x; cv[1] = (bf16)av[r].y;
            cv[2] = (bf16)av[r].z; cv[3] = (bf16)av[r].w;
            *(bf16x4*)(&Al[(r * 32 + arow) * 32 + akk]) = cv;
        }
        #pragma unroll
        for (int r = 0; r < 2; ++r)
            *(bf16x8*)(&Bl[(r * 64 + brow) * 32 + bkk]) = bv[r];
        __syncthreads();

        bf16x8 af[4], bfr[4];
        #pragma unroll
        for (int i = 0; i < 4; ++i)
            af[i] = *(const bf16x8*)(&Al[(wr + i * 16 + fr) * 32 + kq * 8]);
        #pragma unroll
        for (int i = 0; i < 4; ++i)
            bfr[i] = *(const bf16x8*)(&Bl[(wc + i * 16 + fr) * 32 + kq * 8]);
        #pragma unroll
        for (int i = 0; i < 4; ++i)
            #pragma unroll
            for (int j = 0; j < 4; ++j)
                acc[i][j] = __builtin_amdgcn_mfma_f32_16x16x32_bf16(af[i], bfr[j], acc[i][j], 0, 0, 0);
    }

    // epilogue: C row = (lane>>4)*4 + r, col = lane&15
    #pragma unroll
    for (int i = 0; i < 4; ++i)
        #pragma unroll
        for (int j = 0; j < 4; ++j) {
            const int row = m0 + wr + i * 16 + kq * 4;
            const int col = n0 + wc + j * 16 + fr;
            #pragma unroll
            for (int r = 0; r < 4; ++r)
                Y[(size_t)(row + r) * HH + col] = (bf16)acc[i][j][r];
        }
}

// ---------------- K2: per-chunk Horner partial  P_c = beta * sum a^{L-1-j} w_j
// one wave per (c,b); lane handles 8 consecutive h
__global__ void k_chunk(const bf16* __restrict__ Y, const float* __restrict__ alpha,
                        float* __restrict__ P) {
    const int c = blockIdx.x, b = blockIdx.y;
    const int lane = threadIdx.x;
    const int h0 = lane * 8;
    float a[8], p[8];
    #pragma unroll
    for (int k = 0; k < 8; ++k) {
        a[k] = fminf(fmaxf(alpha[h0 + k], ALPHA_LO), ALPHA_HI);
        p[k] = 0.f;
    }
    const bf16* base = Y + ((size_t)b * TT + (size_t)c * LCH) * HH + h0;
    for (int j = 0; j < LCH; ++j) {
        bf16x8 w = *(const bf16x8*)(base + (size_t)j * HH);
        #pragma unroll
        for (int k = 0; k < 8; ++k) p[k] = a[k] * p[k] + (float)w[k];
    }
    float* po = P + ((size_t)c * BATCH + b) * HH + h0;
    #pragma unroll
    for (int k = 0; k < 8; ++k) po[k] = (1.f - a[k]) * p[k];
}

// ---------------- K3: sequential prefix over chunks: V[c] = u_{cL-1} --------
__global__ void k_prefix(const float* __restrict__ alpha, const float* __restrict__ u0,
                         const float* __restrict__ P, float* __restrict__ V) {
    const int g = blockIdx.x * 256 + threadIdx.x;   // 0..B*H-1
    const int h = g & (HH - 1);
    float a = fminf(fmaxf(alpha[h], ALPHA_LO), ALPHA_HI);
    // a^50 by exact chain: ((a^5)^5)^2
    float a2 = a * a, a4 = a2 * a2, a5 = a4 * a;
    float b2 = a5 * a5, b4 = b2 * b2, a25 = b4 * a5;
    float aL = a25 * a25;
    float v = u0[g];
    for (int c = 0; c < CCH; ++c) {
        const size_t idx = (size_t)c * (BATCH * HH) + g;
        V[idx] = v;
        v = aL * v + P[idx];
    }
}

// ---------------- K4: per-chunk softmax accumulate --------------------------
__global__ void k_soft(const bf16* __restrict__ Y, const float* __restrict__ alpha,
                       const float* __restrict__ V, float* __restrict__ OutP) {
    const int c = blockIdx.x, b = blockIdx.y;
    const int lane = threadIdx.x;
    const int h0 = lane * 8;
    float a[8], bt[8], u[8], o[8];
    #pragma unroll
    for (int k = 0; k < 8; ++k) {
        a[k]  = fminf(fmaxf(alpha[h0 + k], ALPHA_LO), ALPHA_HI);
        bt[k] = 1.f - a[k];
        o[k]  = 0.f;
    }
    const float* vb = V + ((size_t)c * BATCH + b) * HH + h0;
    #pragma unroll
    for (int k = 0; k < 8; ++k) u[k] = vb[k];
    const bf16* base = Y + ((size_t)b * TT + (size_t)c * LCH) * HH + h0;
    for (int j = 0; j < LCH; ++j) {
        bf16x8 w = *(const bf16x8*)(base + (size_t)j * HH);
        float e[8], s = 0.f;
        #pragma unroll
        for (int k = 0; k < 8; ++k) {
            u[k] = a[k] * u[k] + bt[k] * (float)w[k];
            e[k] = __expf(u[k]);
            s += e[k];
        }
        #pragma unroll
        for (int off = 32; off >= 1; off >>= 1) s += __shfl_xor(s, off, 64);
        const float inv = 1.f / s;
        #pragma unroll
        for (int k = 0; k < 8; ++k) o[k] += e[k] * inv;
    }
    float* po = OutP + ((size_t)c * BATCH + b) * HH + h0;
    #pragma unroll
    for (int k = 0; k < 8; ++k) po[k] = o[k];
}

// ---------------- K5: reduce chunk partials -> out --------------------------
__global__ void k_reduce(const float* __restrict__ OutP, float* __restrict__ out) {
    const int g = blockIdx.x * 256 + threadIdx.x;
    float s = 0.f;
    for (int c = 0; c < CCH; ++c) s += OutP[(size_t)c * (BATCH * HH) + g];
    out[g] = s;
}

extern "C" void kernel_launch(void* const* d_in, const int* in_sizes, int n_in,
                              void* d_out, int out_size, void* d_ws, size_t ws_size,
                              hipStream_t stream) {
    const float* x     = (const float*)d_in[0];   // [B,T,I]
    const float* W     = (const float*)d_in[1];   // [H,I]
    const float* alpha = (const float*)d_in[2];   // [H]
    const float* u0    = (const float*)d_in[3];   // [B,H]
    float* out = (float*)d_out;                   // [B,H]

    char* ws = (char*)d_ws;
    bf16* Wb = (bf16*)ws;                                   //   0.5 MB
    bf16* Yx = (bf16*)(ws + 524288);                        // 131.1 MB
    float* P = (float*)(ws + 524288 + 131072000);           //   5.2 MB
    float* V = P + (size_t)CCH * BATCH * HH;                //   5.2 MB
    float* OutP = V + (size_t)CCH * BATCH * HH;             //   5.2 MB

    hipLaunchKernelGGL(k_convW,  dim3(256),                  dim3(256), 0, stream, W, Wb);
    hipLaunchKernelGGL(k_gemm,   dim3((MM/128)*(HH/128)),    dim3(256), 0, stream, x, Wb, Yx);
    hipLaunchKernelGGL(k_chunk,  dim3(CCH, BATCH),           dim3(64),  0, stream, Yx, alpha, P);
    hipLaunchKernelGGL(k_prefix, dim3(BATCH*HH/256),         dim3(256), 0, stream, alpha, u0, P, V);
    hipLaunchKernelGGL(k_soft,   dim3(CCH, BATCH),           dim3(64),  0, stream, Yx, alpha, V, OutP);
    hipLaunchKernelGGL(k_reduce, dim3(BATCH*HH/256),         dim3(256), 0, stream, OutP, out);
}

// Round 2
// 204.599 us; speedup vs baseline: 1.2407x; 1.2407x over previous
//
#include <hip/hip_runtime.h>
#include <hip/hip_bf16.h>
#include <stdint.h>

#define ALPHA_LO 0.8187307530779818f
#define ALPHA_HI 0.9607894391523232f

#define BATCH 64
#define TT    2000
#define II    512
#define HH    512
#define MM    (BATCH*TT)
#define LCH   50
#define CCH   (TT/LCH)

typedef __bf16 bf16;
typedef bf16  bf16x8 __attribute__((ext_vector_type(8)));
typedef bf16  bf16x4 __attribute__((ext_vector_type(4)));
typedef float f32x4  __attribute__((ext_vector_type(4)));

// ---------------- K0: convert + transpose W f32 -> bf16 staged layout ------
// Wbt[ntile][k0][kq][r][8]  (ntile:2, k0:16, kq:4, r:256, e:8)
// Wbt[...] = W[ntile*256 + r][k0*32 + kq*8 + e]
__global__ void k_convW(const float* __restrict__ W, bf16* __restrict__ Wbt) {
    const int t  = blockIdx.x * 256 + threadIdx.x;   // 0..32767
    const int h  = t >> 6;           // 0..511
    const int kb = t & 63;           // 8-float group
    const float* src = W + (size_t)h * II + kb * 8;
    float4 v0 = *(const float4*)(src);
    float4 v1 = *(const float4*)(src + 4);
    bf16x8 o;
    o[0]=(bf16)v0.x; o[1]=(bf16)v0.y; o[2]=(bf16)v0.z; o[3]=(bf16)v0.w;
    o[4]=(bf16)v1.x; o[5]=(bf16)v1.y; o[6]=(bf16)v1.z; o[7]=(bf16)v1.w;
    const int ntile = h >> 8, r = h & 255, k0 = kb >> 2, kq = kb & 3;
    bf16* dst = Wbt + (size_t)ntile * 131072 + k0 * 8192 + kq * 2048 + r * 8;
    *(bf16x8*)dst = o;
}

// ---------------- K1: GEMM  Y[M,H] = X[M,I] * W[H,I]^T  (bf16 MFMA) --------
// block tile 128x256, BK=32, 4 waves (2m x 2n), wave tile 64x128.
// LDS layouts: Al[kq][128][8], Bl[kq][256][8]  -> conflict-free b128 frag reads.
__global__ __launch_bounds__(256, 2) void k_gemm(const float* __restrict__ X,
                                                 const bf16* __restrict__ Wbt,
                                                 bf16* __restrict__ Y) {
    __shared__ bf16 Al[4 * 128 * 8];   //  8 KB
    __shared__ bf16 Bl[4 * 256 * 8];   // 16 KB
    const int tid  = threadIdx.x;
    const int bx   = blockIdx.x;
    const int m0   = (bx >> 1) * 128;  // n-fastest: paired n-tiles share x via cache
    const int nt   = bx & 1;
    const int lane = tid & 63;
    const int wv   = tid >> 6;
    const int wr   = (wv >> 1) * 64;
    const int wc   = (wv & 1) * 128;
    const int fr   = lane & 15;
    const int kq   = lane >> 4;

    f32x4 acc[4][8] = {};

    // A staging: thread -> (row = tid>>1, 16-float half = tid&1)
    const int ar  = tid >> 1;
    const int acq = tid & 1;
    const float* xa = X + (size_t)(m0 + ar) * II + acq * 16;
    bf16* aw0 = &Al[(acq * 2) * 1024 + ar * 8];
    bf16* aw1 = aw0 + 1024;

    // B staging: identity copy of pre-transposed chunk (global image == LDS image)
    const bf16* wsrc = Wbt + (size_t)nt * 131072 + wv * 512 + lane * 8;

    float4 av[4];
    #pragma unroll
    for (int q = 0; q < 4; ++q) av[q] = *(const float4*)(xa + q * 4);

    for (int ks = 0; ks < 16; ++ks) {
        __syncthreads();
        // stage A (cvt f32->bf16, conflict-free writes)
        bf16x8 c0, c1;
        c0[0]=(bf16)av[0].x; c0[1]=(bf16)av[0].y; c0[2]=(bf16)av[0].z; c0[3]=(bf16)av[0].w;
        c0[4]=(bf16)av[1].x; c0[5]=(bf16)av[1].y; c0[6]=(bf16)av[1].z; c0[7]=(bf16)av[1].w;
        c1[0]=(bf16)av[2].x; c1[1]=(bf16)av[2].y; c1[2]=(bf16)av[2].z; c1[3]=(bf16)av[2].w;
        c1[4]=(bf16)av[3].x; c1[5]=(bf16)av[3].y; c1[6]=(bf16)av[3].z; c1[7]=(bf16)av[3].w;
        *(bf16x8*)aw0 = c0;
        *(bf16x8*)aw1 = c1;
        // stage B: 4x global_load_lds 16B, identity layout
        #pragma unroll
        for (int q = 0; q < 4; ++q)
            __builtin_amdgcn_global_load_lds(
                (const __attribute__((address_space(1))) unsigned int*)(wsrc + (size_t)ks * 8192 + q * 2048),
                (__attribute__((address_space(3))) unsigned int*)(&Bl[q * 2048 + wv * 512]),
                16, 0, 0);
        // prefetch next A into regs (overlaps with staging/barrier)
        if (ks < 15) {
            #pragma unroll
            for (int q = 0; q < 4; ++q)
                av[q] = *(const float4*)(xa + (ks + 1) * 32 + q * 4);
        }
        __syncthreads();

        bf16x8 af[4], bfr[8];
        #pragma unroll
        for (int i = 0; i < 4; ++i)
            af[i] = *(const bf16x8*)(&Al[kq * 1024 + (wr + i * 16 + fr) * 8]);
        #pragma unroll
        for (int j = 0; j < 8; ++j)
            bfr[j] = *(const bf16x8*)(&Bl[kq * 2048 + (wc + j * 16 + fr) * 8]);
        #pragma unroll
        for (int i = 0; i < 4; ++i)
            #pragma unroll
            for (int j = 0; j < 8; ++j)
                acc[i][j] = __builtin_amdgcn_mfma_f32_16x16x32_bf16(af[i], bfr[j], acc[i][j], 0, 0, 0);
    }

    // epilogue: C row = (lane>>4)*4 + r, col = lane&15
    const int n0 = nt * 256;
    #pragma unroll
    for (int i = 0; i < 4; ++i)
        #pragma unroll
        for (int j = 0; j < 8; ++j) {
            const int row = m0 + wr + i * 16 + kq * 4;
            const int col = n0 + wc + j * 16 + fr;
            #pragma unroll
            for (int r = 0; r < 4; ++r)
                Y[(size_t)(row + r) * HH + col] = (bf16)acc[i][j][r];
        }
}

// ---------------- K2: per-chunk Horner partial ------------------------------
__global__ void k_chunk(const bf16* __restrict__ Y, const float* __restrict__ alpha,
                        float* __restrict__ P) {
    const int c = blockIdx.x, b = blockIdx.y;
    const int lane = threadIdx.x;
    const int h0 = lane * 8;
    float a[8], p[8];
    #pragma unroll
    for (int k = 0; k < 8; ++k) {
        a[k] = fminf(fmaxf(alpha[h0 + k], ALPHA_LO), ALPHA_HI);
        p[k] = 0.f;
    }
    const bf16* base = Y + ((size_t)b * TT + (size_t)c * LCH) * HH + h0;
    for (int j = 0; j < LCH; ++j) {
        bf16x8 w = *(const bf16x8*)(base + (size_t)j * HH);
        #pragma unroll
        for (int k = 0; k < 8; ++k) p[k] = a[k] * p[k] + (float)w[k];
    }
    float* po = P + ((size_t)c * BATCH + b) * HH + h0;
    #pragma unroll
    for (int k = 0; k < 8; ++k) po[k] = (1.f - a[k]) * p[k];
}

// ---------------- K3: sequential prefix over chunks -------------------------
__global__ void k_prefix(const float* __restrict__ alpha, const float* __restrict__ u0,
                         const float* __restrict__ P, float* __restrict__ V) {
    const int g = blockIdx.x * 256 + threadIdx.x;
    const int h = g & (HH - 1);
    float a = fminf(fmaxf(alpha[h], ALPHA_LO), ALPHA_HI);
    float a2 = a * a, a4 = a2 * a2, a5 = a4 * a;
    float b2 = a5 * a5, b4 = b2 * b2, a25 = b4 * a5;
    float aL = a25 * a25;
    float v = u0[g];
    for (int c = 0; c < CCH; ++c) {
        const size_t idx = (size_t)c * (BATCH * HH) + g;
        V[idx] = v;
        v = aL * v + P[idx];
    }
}

// ---------------- K4: per-chunk softmax accumulate --------------------------
__global__ void k_soft(const bf16* __restrict__ Y, const float* __restrict__ alpha,
                       const float* __restrict__ V, float* __restrict__ OutP) {
    const int c = blockIdx.x, b = blockIdx.y;
    const int lane = threadIdx.x;
    const int h0 = lane * 8;
    float a[8], bt[8], u[8], o[8];
    #pragma unroll
    for (int k = 0; k < 8; ++k) {
        a[k]  = fminf(fmaxf(alpha[h0 + k], ALPHA_LO), ALPHA_HI);
        bt[k] = 1.f - a[k];
        o[k]  = 0.f;
    }
    const float* vb = V + ((size_t)c * BATCH + b) * HH + h0;
    #pragma unroll
    for (int k = 0; k < 8; ++k) u[k] = vb[k];
    const bf16* base = Y + ((size_t)b * TT + (size_t)c * LCH) * HH + h0;
    for (int j = 0; j < LCH; ++j) {
        bf16x8 w = *(const bf16x8*)(base + (size_t)j * HH);
        float e[8], s = 0.f;
        #pragma unroll
        for (int k = 0; k < 8; ++k) {
            u[k] = a[k] * u[k] + bt[k] * (float)w[k];
            e[k] = __expf(u[k]);
            s += e[k];
        }
        #pragma unroll
        for (int off = 32; off >= 1; off >>= 1) s += __shfl_xor(s, off, 64);
        const float inv = 1.f / s;
        #pragma unroll
        for (int k = 0; k < 8; ++k) o[k] += e[k] * inv;
    }
    float* po = OutP + ((size_t)c * BATCH + b) * HH + h0;
    #pragma unroll
    for (int k = 0; k < 8; ++k) po[k] = o[k];
}

// ---------------- K5: reduce chunk partials -> out --------------------------
__global__ void k_reduce(const float* __restrict__ OutP, float* __restrict__ out) {
    const int g = blockIdx.x * 256 + threadIdx.x;
    float s = 0.f;
    for (int c = 0; c < CCH; ++c) s += OutP[(size_t)c * (BATCH * HH) + g];
    out[g] = s;
}

extern "C" void kernel_launch(void* const* d_in, const int* in_sizes, int n_in,
                              void* d_out, int out_size, void* d_ws, size_t ws_size,
                              hipStream_t stream) {
    const float* x     = (const float*)d_in[0];
    const float* W     = (const float*)d_in[1];
    const float* alpha = (const float*)d_in[2];
    const float* u0    = (const float*)d_in[3];
    float* out = (float*)d_out;

    char* ws = (char*)d_ws;
    bf16* Wbt = (bf16*)ws;                                  //   0.5 MB
    bf16* Yx  = (bf16*)(ws + 524288);                       // 131.1 MB
    float* P  = (float*)(ws + 524288 + 131072000);
    float* V  = P + (size_t)CCH * BATCH * HH;
    float* OutP = V + (size_t)CCH * BATCH * HH;

    hipLaunchKernelGGL(k_convW,  dim3(128),               dim3(256), 0, stream, W, Wbt);
    hipLaunchKernelGGL(k_gemm,   dim3((MM/128) * 2),      dim3(256), 0, stream, x, Wbt, Yx);
    hipLaunchKernelGGL(k_chunk,  dim3(CCH, BATCH),        dim3(64),  0, stream, Yx, alpha, P);
    hipLaunchKernelGGL(k_prefix, dim3(BATCH*HH/256),      dim3(256), 0, stream, alpha, u0, P, V);
    hipLaunchKernelGGL(k_soft,   dim3(CCH, BATCH),        dim3(64),  0, stream, Yx, alpha, V, OutP);
    hipLaunchKernelGGL(k_reduce, dim3(BATCH*HH/256),      dim3(256), 0, stream, OutP, out);
}

// Round 3
// 176.125 us; speedup vs baseline: 1.4413x; 1.1617x over previous
//
#include <hip/hip_runtime.h>
#include <hip/hip_bf16.h>
#include <stdint.h>

#define ALPHA_LO 0.8187307530779818f
#define ALPHA_HI 0.9607894391523232f

#define BATCH 64
#define TT    2000
#define II    512
#define HH    512
#define MM    (BATCH*TT)
#define LCH   50
#define CCH   (TT/LCH)

typedef __bf16 bf16;
typedef bf16  bf16x8 __attribute__((ext_vector_type(8)));
typedef float f32x4  __attribute__((ext_vector_type(4)));

#define GLDS(src, dst) __builtin_amdgcn_global_load_lds( \
    (const __attribute__((address_space(1))) unsigned int*)(src), \
    (__attribute__((address_space(3))) unsigned int*)(dst), 16, 0, 0)

// ---------------- K0: convert + transpose W f32 -> bf16 staged image -------
// Wbt[k0:16][col:512][k&31]  == W[col][k]  (so per k-step chunk is the exact
// LDS image [col][32] and B staging is an identity global_load_lds copy)
__global__ void k_convW(const float* __restrict__ W, bf16* __restrict__ Wbt) {
    const int t  = blockIdx.x * 256 + threadIdx.x;   // 0..32767
    const int h  = t >> 6;
    const int kb = t & 63;                           // 8-float group
    const float* src = W + (size_t)h * II + kb * 8;
    float4 v0 = *(const float4*)(src);
    float4 v1 = *(const float4*)(src + 4);
    bf16x8 o;
    o[0]=(bf16)v0.x; o[1]=(bf16)v0.y; o[2]=(bf16)v0.z; o[3]=(bf16)v0.w;
    o[4]=(bf16)v1.x; o[5]=(bf16)v1.y; o[6]=(bf16)v1.z; o[7]=(bf16)v1.w;
    bf16* dst = Wbt + (size_t)(kb >> 2) * 16384 + h * 32 + (kb & 3) * 8;
    *(bf16x8*)dst = o;
}

// ---------------- K1: GEMM  Y[M,H] = X[M,I] * W[H,I]^T  (bf16 MFMA) --------
// block 128x512 (full N), 8 waves (2m x 4n), wave tile 64x128, BK=32.
// Depth-2 prefetch: B via global_load_lds (4 LDS buffers), A via regs (3 bufs).
// Issue order B-before-A makes the compiler's auto vmcnt wait for A regs also
// guarantee B landed -> no vmcnt(0) drain; one raw s_barrier per K-step.
__global__ __launch_bounds__(512, 2) void k_gemm(const float* __restrict__ X,
                                                 const bf16* __restrict__ Wbt,
                                                 bf16* __restrict__ Y) {
    __shared__ bf16 Al[2][128 * 32];   //  16 KB
    __shared__ bf16 Bl[4][512 * 32];   // 128 KB
    const int tid  = threadIdx.x;
    const int m0   = blockIdx.x * 128;
    const int lane = tid & 63;
    const int wv   = tid >> 6;
    const int wr   = (wv >> 2) * 64;
    const int wc   = (wv & 3) * 128;
    const int fr   = lane & 15;
    const int kq   = lane >> 4;

    f32x4 acc[4][8] = {};

    // A staging map: thread -> row=tid>>2, 8-float group tid&3
    const int ar   = tid >> 2;
    const int ak   = (tid & 3) * 8;
    const int aoff = ar * 32 + ak;
    const float* xa = X + (size_t)(m0 + ar) * II + ak;

    // B staging: chunk c=q*8+wv of the 32KB k-step image; lane offset lane*16B
    const bf16* wsrc = Wbt + wv * 512 + lane * 8;

    float4 av[3][2];

    // prologue: B(0), A(0), B(1), A(1)  -- B before A at equal depth
    #pragma unroll
    for (int q = 0; q < 4; ++q) GLDS(wsrc + q * 4096,         &Bl[0][(q * 8 + wv) * 512]);
    av[0][0] = *(const float4*)(xa);
    av[0][1] = *(const float4*)(xa + 4);
    #pragma unroll
    for (int q = 0; q < 4; ++q) GLDS(wsrc + 16384 + q * 4096, &Bl[1][(q * 8 + wv) * 512]);
    av[1][0] = *(const float4*)(xa + 32);
    av[1][1] = *(const float4*)(xa + 36);

    #pragma unroll
    for (int ks = 0; ks < 16; ++ks) {
        const int bcur = ks & 3;   // B LDS buffer
        const int acur = ks & 1;   // A LDS buffer
        const int rcur = ks % 3;   // A reg buffer
        // depth-2 prefetch issue (B first, then A)
        if (ks + 2 < 16) {
            #pragma unroll
            for (int q = 0; q < 4; ++q)
                GLDS(wsrc + (size_t)(ks + 2) * 16384 + q * 4096,
                     &Bl[(ks + 2) & 3][(q * 8 + wv) * 512]);
            av[(ks + 2) % 3][0] = *(const float4*)(xa + (size_t)(ks + 2) * 32);
            av[(ks + 2) % 3][1] = *(const float4*)(xa + (size_t)(ks + 2) * 32 + 4);
        }
        // cvt + stage A(ks)  (auto s_waitcnt vmcnt(24) covers A(ks) AND B(ks))
        float4 a0 = av[rcur][0], a1 = av[rcur][1];
        bf16x8 c;
        c[0]=(bf16)a0.x; c[1]=(bf16)a0.y; c[2]=(bf16)a0.z; c[3]=(bf16)a0.w;
        c[4]=(bf16)a1.x; c[5]=(bf16)a1.y; c[6]=(bf16)a1.z; c[7]=(bf16)a1.w;
        *(bf16x8*)(&Al[acur][aoff]) = c;
        asm volatile("s_waitcnt lgkmcnt(0)" ::: "memory");
        __builtin_amdgcn_s_barrier();
        // fragment reads (conflict-free [row][32] layout)
        bf16x8 af[4], bb[8];
        #pragma unroll
        for (int i = 0; i < 4; ++i)
            af[i] = *(const bf16x8*)(&Al[acur][(wr + i * 16 + fr) * 32 + kq * 8]);
        #pragma unroll
        for (int j = 0; j < 8; ++j)
            bb[j] = *(const bf16x8*)(&Bl[bcur][(wc + j * 16 + fr) * 32 + kq * 8]);
        __builtin_amdgcn_s_setprio(1);
        #pragma unroll
        for (int i = 0; i < 4; ++i)
            #pragma unroll
            for (int j = 0; j < 8; ++j)
                acc[i][j] = __builtin_amdgcn_mfma_f32_16x16x32_bf16(af[i], bb[j], acc[i][j], 0, 0, 0);
        __builtin_amdgcn_s_setprio(0);
        asm volatile("" ::: "memory");
    }

    // epilogue: C row = (lane>>4)*4 + r, col = lane&15
    #pragma unroll
    for (int i = 0; i < 4; ++i)
        #pragma unroll
        for (int j = 0; j < 8; ++j) {
            const int row = m0 + wr + i * 16 + kq * 4;
            const int col = wc + j * 16 + fr;
            #pragma unroll
            for (int r = 0; r < 4; ++r)
                Y[(size_t)(row + r) * HH + col] = (bf16)acc[i][j][r];
        }
}

// ---------------- K2: per-chunk Horner partial ------------------------------
__global__ void k_chunk(const bf16* __restrict__ Y, const float* __restrict__ alpha,
                        float* __restrict__ P) {
    const int c = blockIdx.x, b = blockIdx.y;
    const int lane = threadIdx.x;
    const int h0 = lane * 8;
    float a[8], p[8];
    #pragma unroll
    for (int k = 0; k < 8; ++k) {
        a[k] = fminf(fmaxf(alpha[h0 + k], ALPHA_LO), ALPHA_HI);
        p[k] = 0.f;
    }
    const bf16* base = Y + ((size_t)b * TT + (size_t)c * LCH) * HH + h0;
    for (int j = 0; j < LCH; ++j) {
        bf16x8 w = *(const bf16x8*)(base + (size_t)j * HH);
        #pragma unroll
        for (int k = 0; k < 8; ++k) p[k] = a[k] * p[k] + (float)w[k];
    }
    float* po = P + ((size_t)c * BATCH + b) * HH + h0;
    #pragma unroll
    for (int k = 0; k < 8; ++k) po[k] = (1.f - a[k]) * p[k];
}

// ---------------- K3: sequential prefix over chunks -------------------------
__global__ void k_prefix(const float* __restrict__ alpha, const float* __restrict__ u0,
                         const float* __restrict__ P, float* __restrict__ V) {
    const int g = blockIdx.x * 256 + threadIdx.x;
    const int h = g & (HH - 1);
    float a = fminf(fmaxf(alpha[h], ALPHA_LO), ALPHA_HI);
    float a2 = a * a, a4 = a2 * a2, a5 = a4 * a;
    float b2 = a5 * a5, b4 = b2 * b2, a25 = b4 * a5;
    float aL = a25 * a25;
    float v = u0[g];
    for (int c = 0; c < CCH; ++c) {
        const size_t idx = (size_t)c * (BATCH * HH) + g;
        V[idx] = v;
        v = aL * v + P[idx];
    }
}

// ---------------- K4: per-chunk softmax accumulate --------------------------
__global__ void k_soft(const bf16* __restrict__ Y, const float* __restrict__ alpha,
                       const float* __restrict__ V, float* __restrict__ OutP) {
    const int c = blockIdx.x, b = blockIdx.y;
    const int lane = threadIdx.x;
    const int h0 = lane * 8;
    float a[8], bt[8], u[8], o[8];
    #pragma unroll
    for (int k = 0; k < 8; ++k) {
        a[k]  = fminf(fmaxf(alpha[h0 + k], ALPHA_LO), ALPHA_HI);
        bt[k] = 1.f - a[k];
        o[k]  = 0.f;
    }
    const float* vb = V + ((size_t)c * BATCH + b) * HH + h0;
    #pragma unroll
    for (int k = 0; k < 8; ++k) u[k] = vb[k];
    const bf16* base = Y + ((size_t)b * TT + (size_t)c * LCH) * HH + h0;
    for (int j = 0; j < LCH; ++j) {
        bf16x8 w = *(const bf16x8*)(base + (size_t)j * HH);
        float e[8], s = 0.f;
        #pragma unroll
        for (int k = 0; k < 8; ++k) {
            u[k] = a[k] * u[k] + bt[k] * (float)w[k];
            e[k] = __expf(u[k]);
            s += e[k];
        }
        #pragma unroll
        for (int off = 32; off >= 1; off >>= 1) s += __shfl_xor(s, off, 64);
        const float inv = 1.f / s;
        #pragma unroll
        for (int k = 0; k < 8; ++k) o[k] += e[k] * inv;
    }
    float* po = OutP + ((size_t)c * BATCH + b) * HH + h0;
    #pragma unroll
    for (int k = 0; k < 8; ++k) po[k] = o[k];
}

// ---------------- K5: reduce chunk partials -> out --------------------------
__global__ void k_reduce(const float* __restrict__ OutP, float* __restrict__ out) {
    const int g = blockIdx.x * 256 + threadIdx.x;
    float s = 0.f;
    for (int c = 0; c < CCH; ++c) s += OutP[(size_t)c * (BATCH * HH) + g];
    out[g] = s;
}

extern "C" void kernel_launch(void* const* d_in, const int* in_sizes, int n_in,
                              void* d_out, int out_size, void* d_ws, size_t ws_size,
                              hipStream_t stream) {
    const float* x     = (const float*)d_in[0];
    const float* W     = (const float*)d_in[1];
    const float* alpha = (const float*)d_in[2];
    const float* u0    = (const float*)d_in[3];
    float* out = (float*)d_out;

    char* ws = (char*)d_ws;
    bf16* Wbt = (bf16*)ws;                                  //   0.5 MB
    bf16* Yx  = (bf16*)(ws + 524288);                       // 131.1 MB
    float* P  = (float*)(ws + 524288 + 131072000);
    float* V  = P + (size_t)CCH * BATCH * HH;
    float* OutP = V + (size_t)CCH * BATCH * HH;

    hipLaunchKernelGGL(k_convW,  dim3(128),          dim3(256), 0, stream, W, Wbt);
    hipLaunchKernelGGL(k_gemm,   dim3(MM / 128),     dim3(512), 0, stream, x, Wbt, Yx);
    hipLaunchKernelGGL(k_chunk,  dim3(CCH, BATCH),   dim3(64),  0, stream, Yx, alpha, P);
    hipLaunchKernelGGL(k_prefix, dim3(BATCH*HH/256), dim3(256), 0, stream, alpha, u0, P, V);
    hipLaunchKernelGGL(k_soft,   dim3(CCH, BATCH),   dim3(64),  0, stream, Yx, alpha, V, OutP);
    hipLaunchKernelGGL(k_reduce, dim3(BATCH*HH/256), dim3(256), 0, stream, OutP, out);
}